// Round 10
// baseline (34732.001 us; speedup 1.0000x reference)
//
#include <hip/hip_runtime.h>
#include <hip/hip_bf16.h>
#include <math.h>

// Multilayer GRU: B=32, S=512, H=1024, L=3, O=1024.
// v10: v9 (fat-block layer pipeline, 48 blocks = 3 layers x 16 x 1024thr,
// per-block LDS staging with XOR swizzle, L2/L3-served coherent loads) with
// the x-staging index bug fixed: a 1024-bf16 row = 256 u64 words, so the
// linear u64 index decomposes as (idx>>8, idx&255) -- v9 used (>>7, &127),
// scrambling every staged x tile (absmax 0.6).

#define BB 32
#define SS 512
#define HH 1024
#define LL 3
#define OO 1024
#define SH (SS*HH)
#define NBL 16

typedef __attribute__((ext_vector_type(8))) short short8;
typedef __attribute__((ext_vector_type(4))) float float4v;
typedef unsigned long long u64;
typedef unsigned int u32;
typedef unsigned short u16;

__device__ __forceinline__ u16 f2bf(float f) {
  union { float f; u32 u; } v; v.f = f;
  return (u16)((v.u + 0x7FFFu + ((v.u >> 16) & 1u)) >> 16);
}

__global__ void convert_bf16(const float* __restrict__ src,
                             u16* __restrict__ dst, int n) {
  int stride = gridDim.x * blockDim.x;
  for (int i = blockIdx.x * blockDim.x + threadIdx.x; i < n; i += stride)
    dst[i] = f2bf(src[i]);
}

// hb[l][b][c] = bf16(h0[b][l][c])
__global__ void init_h(const float* __restrict__ h0, u16* __restrict__ hb) {
  int i = blockIdx.x * 256 + threadIdx.x;           // 98304 total
  int l = i >> 15, r = i & 32767, b = r >> 10, c = r & 1023;
  hb[i] = f2bf(h0[b * 3072 + l * 1024 + c]);
}

// Pack W[nmat][1024][1024] into MFMA B-fragment stream:
// dst[((row>>4)*32+(k>>5))*512 + lane*8 + (k&7)], lane = ((k>>3)&3)*16+(row&15)
__global__ void pack_w(const float* __restrict__ src, u16* __restrict__ dst,
                       int nmat) {
  int stride = gridDim.x * blockDim.x;
  int total = nmat * 1048576;
  for (int i = blockIdx.x * blockDim.x + threadIdx.x; i < total; i += stride) {
    int m = i >> 20, e = i & 1048575;
    int row = e >> 10, k = e & 1023;
    int lane = ((k >> 3) & 3) * 16 + (row & 15);
    int di = ((row >> 4) * 32 + (k >> 5)) * 512 + lane * 8 + (k & 7);
    dst[m * 1048576 + di] = f2bf(src[i]);
  }
}

// ---- access primitives ----------------------------------------------------
__device__ __forceinline__ u64 aload(const u64* p) {
  return __hip_atomic_load(p, __ATOMIC_RELAXED, __HIP_MEMORY_SCOPE_AGENT);
}
__device__ __forceinline__ int aloadi(const int* p) {
  return __hip_atomic_load(p, __ATOMIC_RELAXED, __HIP_MEMORY_SCOPE_AGENT);
}
__device__ __forceinline__ void coh_store_u16(u16* p, u16 v) {
  u32 vv = v;
  asm volatile("global_store_short %0, %1, off sc0 sc1"
               :: "v"(p), "v"(vv) : "memory");
}
__device__ __forceinline__ void plain_store_u16(u16* p, u16 v) {
  u32 vv = v;
  asm volatile("global_store_short %0, %1, off" :: "v"(p), "v"(vv) : "memory");
}
__device__ __forceinline__ void coh_store_u32(int* p, int v) {
  asm volatile("global_store_dword %0, %1, off sc0 sc1"
               :: "v"(p), "v"(v) : "memory");
}
__device__ __forceinline__ void wait_vm0() {
  asm volatile("s_waitcnt vmcnt(0)" ::: "memory");
}

#define MFMA16(a, b, c) __builtin_amdgcn_mfma_f32_16x16x32_bf16(a, b, c, 0, 0, 0)
#define SWZ(byte) ((byte) ^ ((((byte) >> 11) & 7) << 4))

__launch_bounds__(1024)
__global__ void gru_pipe(
    u16* __restrict__ buf0, u16* __restrict__ buf1,
    const u16* __restrict__ Pzh, const u16* __restrict__ Pzx,
    const u16* __restrict__ Prh, const u16* __restrict__ Prx,
    const u16* __restrict__ Pgh, const u16* __restrict__ Pgx,
    const float* __restrict__ bz, const float* __restrict__ br,
    const float* __restrict__ bg, const float* __restrict__ h0,
    u16* __restrict__ hbA, u16* __restrict__ rhA,
    float* __restrict__ hid, int* __restrict__ fR, int* __restrict__ fH,
    int* __restrict__ prod) {
  __shared__ char ldsA[65536];   // h (phase1) / rh (phase2), XOR-swizzled
  __shared__ char ldsX[65536];   // x_t, XOR-swizzled
  __shared__ float redz[4][4][2][64], redr[4][4][2][64], redg[4][4][2][64];

  const int tid = threadIdx.x;
  const int lane = tid & 63;
  const int w = tid >> 6;                 // 16 waves
  const int cs = w & 3;                   // 16-col subtile
  const int mt = (w >> 2) & 1;            // rows 0-15 / 16-31
  const int side = w >> 3;                // 0 = h-side, 1 = x-side
  const int lay = blockIdx.x >> 4;
  const int blk = blockIdx.x & 15;
  const int fcol = lane & 15, kg = lane >> 4;
  const int row = mt * 16 + fcol;         // A-row (batch)
  const int crow0 = mt * 16 + kg * 4;
  const int colG = blk * 64 + cs * 16 + fcol;

  const u16* xin = (lay & 1) ? buf1 : buf0;
  u16* yout      = (lay & 1) ? buf0 : buf1;
  const size_t lw = (size_t)lay * 1048576;
  const int nb = blk * 4 + cs;
  const u16* wZ  = (side ? Pzx : Pzh) + lw + nb * 16384 + lane * 8;
  const u16* wR  = (side ? Prx : Prh) + lw + nb * 16384 + lane * 8;
  const u16* wGx = Pgx + lw + nb * 16384 + lane * 8;   // side1 only
  const u16* wGh = Pgh + lw + nb * 16384 + lane * 8;
  u16* hbl = hbA + lay * (BB * HH);
  u16* rhl = rhA + lay * (BB * HH);
  int* fRl = fR + lay * NBL;
  int* fHl = fH + lay * NBL;
  int* prodSelf = prod + lay * NBL;
  const int* prodPrev = prod + (lay > 0 ? (lay - 1) * NBL : 0);

  float hreg[4] = {0, 0, 0, 0}, zreg[4] = {0, 0, 0, 0};
  float bzv = 0, brv = 0, bgv = 0;
  if (side == 0) {
#pragma unroll
    for (int q = 0; q < 4; ++q)
      hreg[q] = h0[(crow0 + q) * (LL * HH) + lay * HH + colG];
    bzv = bz[lay * HH + colG];
    brv = br[lay * HH + colG];
    bgv = bg[lay * HH + colG];
  }

  for (int t = 0; t < SS; ++t) {
    // ---- gate 1: all h[t] published (fH >= t); producer y[t] done --------
    if (w == 0) {
      const bool isH = lane < NBL;
      const bool isP = (lane >= 16 && lane < 16 + NBL) && (lay != 0);
      const int* p = isH ? (fHl + lane) : (prodPrev + (lane & 15));
      const int tgt = (isH | isP) ? (isH ? t : t + 1) : 0;
      for (;;) {
        int f = (isH | isP) ? aloadi(p) : 0x7fffffff;
        if (!__any(f < tgt)) break;
        __builtin_amdgcn_s_sleep(2);
      }
    }
    __syncthreads();

    // ---- stage h -> ldsA, x -> ldsX (64KB each, once per block) ----------
#pragma unroll
    for (int hh = 0; hh < 2; ++hh) {
      u64 tmp[4];
#pragma unroll
      for (int j = 0; j < 4; ++j)
        tmp[j] = aload((const u64*)hbl + (hh * 4 + j) * 1024 + tid);
#pragma unroll
      for (int j = 0; j < 4; ++j) {
        int byte = ((hh * 4 + j) * 1024 + tid) * 8;
        *(u64*)(ldsA + SWZ(byte)) = tmp[j];
      }
    }
    {
      const u16* xb = xin + (size_t)t * HH;
      if (lay == 0) {
#pragma unroll
        for (int hh = 0; hh < 2; ++hh) {
          u64 tmp[4];
#pragma unroll
          for (int j = 0; j < 4; ++j) {
            int idx = (hh * 4 + j) * 1024 + tid;
            tmp[j] = *((const u64*)(xb + (size_t)(idx >> 8) * SH) + (idx & 255));
          }
#pragma unroll
          for (int j = 0; j < 4; ++j) {
            int byte = ((hh * 4 + j) * 1024 + tid) * 8;
            *(u64*)(ldsX + SWZ(byte)) = tmp[j];
          }
        }
      } else {
#pragma unroll
        for (int hh = 0; hh < 2; ++hh) {
          u64 tmp[4];
#pragma unroll
          for (int j = 0; j < 4; ++j) {
            int idx = (hh * 4 + j) * 1024 + tid;
            tmp[j] = aload((const u64*)(xb + (size_t)(idx >> 8) * SH) + (idx & 255));
          }
#pragma unroll
          for (int j = 0; j < 4; ++j) {
            int byte = ((hh * 4 + j) * 1024 + tid) * 8;
            *(u64*)(ldsX + SWZ(byte)) = tmp[j];
          }
        }
      }
    }
    __syncthreads();

    // ---- phase 1: z,r over this side's K=1024 (+ gx on side1) ------------
    const char* A1 = side ? ldsX : ldsA;
    float4v az = {0,0,0,0}, ar = {0,0,0,0}, ag = {0,0,0,0};
#pragma unroll
    for (int c0 = 0; c0 < 32; c0 += 8) {
      short8 cf[8];
#pragma unroll
      for (int k = 0; k < 8; ++k) {
        int byte = row * 2048 + (c0 + k) * 64 + kg * 16;
        cf[k] = *(const short8*)(A1 + SWZ(byte));
      }
#pragma unroll
      for (int k = 0; k < 8; ++k) {
        int ks = c0 + k;
        az = MFMA16(cf[k], *(const short8*)(wZ + ks * 512), az);
        ar = MFMA16(cf[k], *(const short8*)(wR + ks * 512), ar);
        if (side) ag = MFMA16(cf[k], *(const short8*)(wGx + ks * 512), ag);
      }
    }
    if (side) {
#pragma unroll
      for (int q = 0; q < 4; ++q) {
        redz[cs][q][mt][lane] = az[q];
        redr[cs][q][mt][lane] = ar[q];
      }
    }
    __syncthreads();

    if (side == 0) {
#pragma unroll
      for (int q = 0; q < 4; ++q) {
        float pz = az[q] + redz[cs][q][mt][lane] + bzv;
        float pr = ar[q] + redr[cs][q][mt][lane] + brv;
        zreg[q] = 1.f / (1.f + expf(-pz));
        float rv = 1.f / (1.f + expf(-pr));
        coh_store_u16(rhl + (crow0 + q) * HH + colG, f2bf(rv * hreg[q]));
      }
      wait_vm0();
    }
    __syncthreads();
    if (tid == 0) coh_store_u32(fRl + blk, t + 1);

    // ---- gate 2: all rh published ---------------------------------------
    if (w == 0) {
      for (;;) {
        int f = (lane < NBL) ? aloadi(fRl + lane) : 0x7fffffff;
        if (!__any(f < ((lane < NBL) ? t + 1 : 0))) break;
        __builtin_amdgcn_s_sleep(2);
      }
    }
    __syncthreads();

    // ---- stage rh -> ldsA ------------------------------------------------
#pragma unroll
    for (int hh = 0; hh < 2; ++hh) {
      u64 tmp[4];
#pragma unroll
      for (int j = 0; j < 4; ++j)
        tmp[j] = aload((const u64*)rhl + (hh * 4 + j) * 1024 + tid);
#pragma unroll
      for (int j = 0; j < 4; ++j) {
        int byte = ((hh * 4 + j) * 1024 + tid) * 8;
        *(u64*)(ldsA + SWZ(byte)) = tmp[j];
      }
    }
    __syncthreads();

    // ---- phase 2: gh over this side's K-half -----------------------------
#pragma unroll
    for (int c0 = 0; c0 < 16; c0 += 8) {
      short8 cf[8];
#pragma unroll
      for (int k = 0; k < 8; ++k) {
        int ks = side * 16 + c0 + k;
        int byte = row * 2048 + ks * 64 + kg * 16;
        cf[k] = *(const short8*)(ldsA + SWZ(byte));
      }
#pragma unroll
      for (int k = 0; k < 8; ++k) {
        int ks = side * 16 + c0 + k;
        ag = MFMA16(cf[k], *(const short8*)(wGh + ks * 512), ag);
      }
    }
    if (side) {
#pragma unroll
      for (int q = 0; q < 4; ++q) redg[cs][q][mt][lane] = ag[q];
    }
    __syncthreads();

    if (side == 0) {
#pragma unroll
      for (int q = 0; q < 4; ++q) {
        float pg = ag[q] + redg[cs][q][mt][lane] + bgv;
        float gv = tanhf(pg);
        float hn = zreg[q] * hreg[q] + (1.f - zreg[q]) * gv;
        hreg[q] = hn;
        u16 hv = f2bf(hn);
        const int rr = crow0 + q;
        coh_store_u16(hbl + rr * HH + colG, hv);
        if (lay < 2)
          coh_store_u16(yout + (size_t)rr * SH + (size_t)t * HH + colG, hv);
        else
          plain_store_u16(yout + (size_t)rr * SH + (size_t)t * HH + colG, hv);
        if (t == SS - 1) hid[rr * (LL * HH) + lay * HH + colG] = hn;
      }
      wait_vm0();
    }
    __syncthreads();
    if (tid == 0) {
      coh_store_u32(fHl + blk, t + 1);
      if (lay < 2) coh_store_u32(prodSelf + blk, t + 1);
    }
  }
}

// C[16384,1024] = A[16384,1024](bf16) @ W^T(bf16 rows) + bo
__launch_bounds__(64)
__global__ void out_gemm(const u16* __restrict__ A, const u16* __restrict__ W,
                         const float* __restrict__ bo, float* __restrict__ C) {
  const int lane = threadIdx.x;
  const int nt4 = blockIdx.x & 15;
  const int mt4 = blockIdx.x >> 4;
  const int r0 = mt4 * 64, n0 = nt4 * 64;
  const int fcol = lane & 15, kg = lane >> 4;
  float4v acc[4][4];
#pragma unroll
  for (int i = 0; i < 4; ++i)
#pragma unroll
    for (int j = 0; j < 4; ++j) acc[i][j] = (float4v){0, 0, 0, 0};

  for (int ks = 0; ks < 32; ++ks) {
    short8 a[4], b[4];
#pragma unroll
    for (int i = 0; i < 4; ++i)
      a[i] = *(const short8*)(A + (size_t)(r0 + i * 16 + fcol) * HH + ks * 32 + kg * 8);
#pragma unroll
    for (int j = 0; j < 4; ++j)
      b[j] = *(const short8*)(W + (size_t)(n0 + j * 16 + fcol) * HH + ks * 32 + kg * 8);
#pragma unroll
    for (int i = 0; i < 4; ++i)
#pragma unroll
      for (int j = 0; j < 4; ++j)
        acc[i][j] = MFMA16(a[i], b[j], acc[i][j]);
  }
#pragma unroll
  for (int i = 0; i < 4; ++i)
#pragma unroll
    for (int j = 0; j < 4; ++j)
#pragma unroll
      for (int q = 0; q < 4; ++q) {
        int R = r0 + i * 16 + kg * 4 + q;
        int col = n0 + j * 16 + fcol;
        C[(size_t)R * OO + col] = acc[i][j][q] + bo[col];
      }
}

extern "C" void kernel_launch(void* const* d_in, const int* in_sizes, int n_in,
                              void* d_out, int out_size, void* d_ws, size_t ws_size,
                              hipStream_t stream) {
  (void)in_sizes; (void)n_in; (void)out_size; (void)ws_size;

  const float* x   = (const float*)d_in[0];
  const float* h0  = (const float*)d_in[1];
  const float* Wzx = (const float*)d_in[2];
  const float* bz  = (const float*)d_in[3];
  const float* Wzh = (const float*)d_in[4];
  const float* Wrx = (const float*)d_in[5];
  const float* br  = (const float*)d_in[6];
  const float* Wrh = (const float*)d_in[7];
  const float* Wgx = (const float*)d_in[8];
  const float* bg  = (const float*)d_in[9];
  const float* Wgh = (const float*)d_in[10];
  const float* Wo  = (const float*)d_in[11];
  const float* bo  = (const float*)d_in[12];
  float* out = (float*)d_out;

  // ws layout (~103 MB)
  u16* Pzh = (u16*)d_ws;
  u16* Pzx = Pzh + 3145728;
  u16* Prh = Pzx + 3145728;
  u16* Prx = Prh + 3145728;
  u16* Pgh = Prx + 3145728;
  u16* Pgx = Pgh + 3145728;
  u16* Wob = Pgx + 3145728;            // 1M elems
  u16* buf0 = Wob + 1048576;           // 16.7M elems
  u16* buf1 = buf0 + 16777216;
  u16* hbA  = buf1 + 16777216;         // [3][32][1024]
  u16* rhA  = hbA + 3 * BB * HH;       // [3][32][1024]
  int* flags = (int*)(rhA + 3 * BB * HH);
  int* fR   = flags;                   // 3*16
  int* fH   = flags + 64;              // 3*16
  int* prod = flags + 128;             // 3*16

  hipMemsetAsync(flags, 0, 256 * sizeof(int), stream);

  pack_w<<<3072, 256, 0, stream>>>(Wzh, Pzh, 3);
  pack_w<<<3072, 256, 0, stream>>>(Wzx, Pzx, 3);
  pack_w<<<3072, 256, 0, stream>>>(Wrh, Prh, 3);
  pack_w<<<3072, 256, 0, stream>>>(Wrx, Prx, 3);
  pack_w<<<3072, 256, 0, stream>>>(Wgh, Pgh, 3);
  pack_w<<<3072, 256, 0, stream>>>(Wgx, Pgx, 3);
  convert_bf16<<<256, 256, 0, stream>>>(Wo, Wob, 1048576);
  convert_bf16<<<2048, 256, 0, stream>>>(x, buf0, 16777216);
  init_h<<<384, 256, 0, stream>>>(h0, hbA);

  gru_pipe<<<48, 1024, 0, stream>>>(
      buf0, buf1, Pzh, Pzx, Prh, Prx, Pgh, Pgx,
      bz, br, bg, h0, hbA, rhA,
      out + 16777216, fR, fH, prod);

  out_gemm<<<4096, 64, 0, stream>>>(buf1, Wob, bo, out);
}

// Round 11
// 14921.437 us; speedup vs baseline: 2.3277x; 2.3277x over previous
//
#include <hip/hip_runtime.h>
#include <hip/hip_bf16.h>
#include <math.h>

// Multilayer GRU: B=32, S=512, H=1024, L=3, O=1024.
// v11: v7 (layer-pipelined 192-block persistent kernel, per-wave gating,
// agent-atomic coherent loads, sc0sc1 write-through stores) plus:
//  (1) h-side weight slices (Wzh,Wrh,Wgh, 96KB/block) staged in LDS once
//      before the t-loop -> post-gate MFMAs read B-frags from LDS.
//  (2) rh/h/y publishes coalesced: wave-local LDS transpose then ONE
//      global_store_dwordx4 sc0sc1 per lane (was 4 scattered 2B stores).

#define BB 32
#define SS 512
#define HH 1024
#define LL 3
#define OO 1024
#define SH (SS*HH)

typedef __attribute__((ext_vector_type(8))) short short8;
typedef __attribute__((ext_vector_type(4))) float float4v;
typedef unsigned long long u64;
typedef unsigned int u32;
typedef unsigned short u16;

__device__ __forceinline__ u16 f2bf(float f) {
  union { float f; u32 u; } v; v.f = f;
  return (u16)((v.u + 0x7FFFu + ((v.u >> 16) & 1u)) >> 16);
}

__global__ void convert_bf16(const float* __restrict__ src,
                             u16* __restrict__ dst, int n) {
  int stride = gridDim.x * blockDim.x;
  for (int i = blockIdx.x * blockDim.x + threadIdx.x; i < n; i += stride)
    dst[i] = f2bf(src[i]);
}

// hb[l][b][c] = bf16(h0[b][l][c])
__global__ void init_h(const float* __restrict__ h0, u16* __restrict__ hb) {
  int i = blockIdx.x * 256 + threadIdx.x;           // 98304 total
  int l = i >> 15, r = i & 32767, b = r >> 10, c = r & 1023;
  hb[i] = f2bf(h0[b * 3072 + l * 1024 + c]);
}

// Pack W[nmat][1024][1024] into MFMA B-fragment stream:
// dst[((row>>4)*32+(k>>5))*512 + lane*8 + (k&7)], lane = ((k>>3)&3)*16+(row&15)
__global__ void pack_w(const float* __restrict__ src, u16* __restrict__ dst,
                       int nmat) {
  int stride = gridDim.x * blockDim.x;
  int total = nmat * 1048576;
  for (int i = blockIdx.x * blockDim.x + threadIdx.x; i < total; i += stride) {
    int m = i >> 20, e = i & 1048575;
    int row = e >> 10, k = e & 1023;
    int lane = ((k >> 3) & 3) * 16 + (row & 15);
    int di = ((row >> 4) * 32 + (k >> 5)) * 512 + lane * 8 + (k & 7);
    dst[m * 1048576 + di] = f2bf(src[i]);
  }
}

// ---- access primitives ----------------------------------------------------
// coherent L3/L2-served 16B fragment load (2 x 8B agent-scope atomic loads)
__device__ __forceinline__ short8 coh16(const u16* p) {
  const u64* q = (const u64*)p;
  union { u64 q[2]; short8 v; } u;
  u.q[0] = __hip_atomic_load(q,     __ATOMIC_RELAXED, __HIP_MEMORY_SCOPE_AGENT);
  u.q[1] = __hip_atomic_load(q + 1, __ATOMIC_RELAXED, __HIP_MEMORY_SCOPE_AGENT);
  return u.v;
}
__device__ __forceinline__ void coh_store16(u16* p, short8 v) {
  asm volatile("global_store_dwordx4 %0, %1, off sc0 sc1"
               :: "v"(p), "v"(v) : "memory");
}
__device__ __forceinline__ void coh_store_u32(int* p, int v) {
  asm volatile("global_store_dword %0, %1, off sc0 sc1"
               :: "v"(p), "v"(v) : "memory");
}
// poll 128 flags (2 per lane) until all >= tgt; backoff between rounds
__device__ __forceinline__ void poll2(const int* base, int lane, int tgt) {
  const int* p0 = base + lane;
  const int* p1 = base + 64 + lane;
  int f0 = __hip_atomic_load(p0, __ATOMIC_RELAXED, __HIP_MEMORY_SCOPE_AGENT);
  int f1 = __hip_atomic_load(p1, __ATOMIC_RELAXED, __HIP_MEMORY_SCOPE_AGENT);
  while (__any((f0 < tgt) | (f1 < tgt))) {
    __builtin_amdgcn_s_sleep(1);
    f0 = __hip_atomic_load(p0, __ATOMIC_RELAXED, __HIP_MEMORY_SCOPE_AGENT);
    f1 = __hip_atomic_load(p1, __ATOMIC_RELAXED, __HIP_MEMORY_SCOPE_AGENT);
  }
}

#define MFMA16(a, b, c) __builtin_amdgcn_mfma_f32_16x16x32_bf16(a, b, c, 0, 0, 0)

__launch_bounds__(256, 1)
__global__ void gru_pipe(
    u16* __restrict__ buf0, u16* __restrict__ buf1,
    const u16* __restrict__ Pzh, const u16* __restrict__ Pzx,
    const u16* __restrict__ Prh, const u16* __restrict__ Prx,
    const u16* __restrict__ Pgh, const u16* __restrict__ Pgx,
    const float* __restrict__ bz, const float* __restrict__ br,
    const float* __restrict__ bg, const float* __restrict__ h0,
    u16* __restrict__ hb, u16* __restrict__ rh,
    float* __restrict__ hid, int* __restrict__ flagsD,
    int* __restrict__ flagsP) {
  __shared__ __align__(16) u16 smW[3][16384];     // Wzh, Wrh, Wgh (96 KB)
  __shared__ float redz[4][2][64], redr[4][2][64], redg[4][2][64];
  __shared__ __align__(16) u16 pub[2][16][16];    // per-mt transpose buffer

  const int grp = blockIdx.x >> 6;        // layer 0..2
  const int blk = blockIdx.x & 63;        // 16-col tile
  const int tid = threadIdx.x;
  const int lane = tid & 63;
  const int wave = tid >> 6;
  const int mt = wave & 1;                // M-tile: rows 0-15 / 16-31
  const int kh = wave >> 1;               // phase1 side: 0=h, 1=x
  const int fcol = lane & 15, kg = lane >> 4;
  const int arow = mt * 16 + fcol;
  const int crow0 = mt * 16 + kg * 4;
  const int colZ = blk * 16 + fcol;

  const u16* xin = (grp & 1) ? buf1 : buf0;
  u16* yout      = (grp & 1) ? buf0 : buf1;
  const size_t lw = (size_t)grp * 1048576;
  // x-side weights stream from cache (overlap the waits)
  const u16* wZx = Pzx + lw + blk * 16384 + lane * 8;
  const u16* wRx = Prx + lw + blk * 16384 + lane * 8;
  const u16* wGx = Pgx + lw + blk * 16384 + lane * 8;
  u16* hbl = hb + grp * (BB * HH);
  u16* rhl = rh + grp * (BB * HH);
  int* selfD = flagsD + (grp + 1) * 128;
  int* prodD = flagsD + grp * 128;
  int* selfP = flagsP + grp * 128;

  // ---- stage h-side weight slices into LDS (once) -------------------------
  {
    const u64* g0 = (const u64*)(Pzh + lw + blk * 16384);
    const u64* g1 = (const u64*)(Prh + lw + blk * 16384);
    const u64* g2 = (const u64*)(Pgh + lw + blk * 16384);
    u64* d0 = (u64*)smW[0];
    u64* d1 = (u64*)smW[1];
    u64* d2 = (u64*)smW[2];
#pragma unroll
    for (int j = 0; j < 16; ++j) {
      d0[j * 256 + tid] = g0[j * 256 + tid];
      d1[j * 256 + tid] = g1[j * 256 + tid];
      d2[j * 256 + tid] = g2[j * 256 + tid];
    }
  }
  __syncthreads();
  const u16* lZ = smW[0] + lane * 8;
  const u16* lR = smW[1] + lane * 8;
  const u16* lG = smW[2] + lane * 8;

  float hreg[4] = {0, 0, 0, 0}, zreg[4] = {0, 0, 0, 0};
  float bzv = 0, brv = 0, bgv = 0;
  if (kh == 0) {
#pragma unroll
    for (int q = 0; q < 4; ++q)
      hreg[q] = h0[(crow0 + q) * (LL * HH) + grp * HH + colZ];
    bzv = bz[grp * HH + colZ];
    brv = br[grp * HH + colZ];
    bgv = bg[grp * HH + colZ];
  }

  const u16* Ah = hbl + arow * HH;
  const u16* Ax = xin + (size_t)arow * SH;
  const u16* Ar = rhl + arow * HH + kh * 512;   // phase2 K-half base
  const bool xcoh = (grp != 0);                 // layer0 x: plain cached

  for (int t = 0; t < SS; ++t) {
    // ---- phase-1 gate (per-wave): kh0 needs own-layer WAR; kh1 needs x[t]
    if (kh == 0)      poll2(selfD, lane, t);
    else if (xcoh)    poll2(prodD, lane, t + 1);

    float4v az0 = {0,0,0,0}, az1 = {0,0,0,0};
    float4v ar0 = {0,0,0,0}, ar1 = {0,0,0,0};
    float4v ag0 = {0,0,0,0}, ag1 = {0,0,0,0};
    short8 cf[16];

    if (kh == 0) {
      // ---- h-side z,r GEMM: A coherent, B from LDS ----
#pragma unroll
      for (int c0 = 0; c0 < 32; c0 += 16) {
#pragma unroll
        for (int k = 0; k < 16; ++k)
          cf[k] = coh16(Ah + (c0 + k) * 32 + kg * 8);
#pragma unroll
        for (int k = 0; k < 16; ++k) {
          short8 vz = *(const short8*)(lZ + (c0 + k) * 512);
          short8 vr = *(const short8*)(lR + (c0 + k) * 512);
          if (k & 1) { az1 = MFMA16(cf[k], vz, az1); ar1 = MFMA16(cf[k], vr, ar1); }
          else       { az0 = MFMA16(cf[k], vz, az0); ar0 = MFMA16(cf[k], vr, ar0); }
        }
      }
    } else {
      // ---- x-side z,r (+gx) GEMM: A coherent/plain, B streamed ----
      const u16* A1 = Ax + (size_t)t * HH;
#pragma unroll
      for (int c0 = 0; c0 < 32; c0 += 16) {
        if (xcoh) {
#pragma unroll
          for (int k = 0; k < 16; ++k)
            cf[k] = coh16(A1 + (c0 + k) * 32 + kg * 8);
        } else {
#pragma unroll
          for (int k = 0; k < 16; ++k)
            cf[k] = *(const short8*)(A1 + (c0 + k) * 32 + kg * 8);
        }
#pragma unroll
        for (int k = 0; k < 16; ++k) {
          int ks = c0 + k;
          short8 vz = *(const short8*)(wZx + ks * 512);
          short8 vr = *(const short8*)(wRx + ks * 512);
          short8 vg = *(const short8*)(wGx + ks * 512);
          if (k & 1) { az1 = MFMA16(cf[k], vz, az1); ar1 = MFMA16(cf[k], vr, ar1);
                       ag1 = MFMA16(cf[k], vg, ag1); }
          else       { az0 = MFMA16(cf[k], vz, az0); ar0 = MFMA16(cf[k], vr, ar0);
                       ag0 = MFMA16(cf[k], vg, ag0); }
        }
      }
#pragma unroll
      for (int q = 0; q < 4; ++q) {
        redz[q][mt][lane] = az0[q] + az1[q];
        redr[q][mt][lane] = ar0[q] + ar1[q];
      }
    }
    __syncthreads();

    if (kh == 0) {
      // finalize z,r; transpose-publish r*h (one dwordx4/lane); flag
#pragma unroll
      for (int q = 0; q < 4; ++q) {
        float pz = az0[q] + az1[q] + redz[q][mt][lane] + bzv;
        float pr = ar0[q] + ar1[q] + redr[q][mt][lane] + brv;
        zreg[q] = 1.f / (1.f + expf(-pz));
        float rv = 1.f / (1.f + expf(-pr));
        pub[mt][kg * 4 + q][fcol] = f2bf(rv * hreg[q]);
      }
      asm volatile("s_waitcnt lgkmcnt(0)" ::: "memory");
      __builtin_amdgcn_sched_barrier(0);
      if (lane < 32) {
        int r = lane >> 1, c8 = (lane & 1) * 8;
        short8 v = *(const short8*)&pub[mt][r][c8];
        coh_store16(rhl + (mt * 16 + r) * HH + blk * 16 + c8, v);
      }
      asm volatile("s_waitcnt vmcnt(0)" ::: "memory");
      if (lane == 0) coh_store_u32(selfP + blk * 2 + mt, t + 1);
    }

    // ---- phase-2 gate: all r*h published
    poll2(selfP, lane, t + 1);

    // rh frags: 16 per wave (K split by kh); B from LDS (Wgh)
#pragma unroll
    for (int k = 0; k < 16; ++k) cf[k] = coh16(Ar + k * 32 + kg * 8);
#pragma unroll
    for (int k = 0; k < 16; ++k) {
      short8 vg = *(const short8*)(lG + (kh * 16 + k) * 512);
      if (k & 1) ag1 = MFMA16(cf[k], vg, ag1);
      else       ag0 = MFMA16(cf[k], vg, ag0);
    }
    if (kh == 1) {
#pragma unroll
      for (int q = 0; q < 4; ++q) redg[q][mt][lane] = ag0[q] + ag1[q];
    }
    __syncthreads();

    if (kh == 0) {
#pragma unroll
      for (int q = 0; q < 4; ++q) {
        float pg = ag0[q] + ag1[q] + redg[q][mt][lane] + bgv;
        float gv = tanhf(pg);
        float hn = zreg[q] * hreg[q] + (1.f - zreg[q]) * gv;
        hreg[q] = hn;
        pub[mt][kg * 4 + q][fcol] = f2bf(hn);
        if (t == SS - 1) hid[(crow0 + q) * (LL * HH) + grp * HH + colZ] = hn;
      }
      asm volatile("s_waitcnt lgkmcnt(0)" ::: "memory");
      __builtin_amdgcn_sched_barrier(0);
      if (lane < 32) {
        int r = lane >> 1, c8 = (lane & 1) * 8;
        short8 v = *(const short8*)&pub[mt][r][c8];
        const int row = mt * 16 + r;
        coh_store16(hbl + row * HH + blk * 16 + c8, v);
        coh_store16(yout + (size_t)row * SH + (size_t)t * HH + blk * 16 + c8, v);
      }
      asm volatile("s_waitcnt vmcnt(0)" ::: "memory");
      if (lane == 0) coh_store_u32(selfD + blk * 2 + mt, t + 1);
    }
  }
}

// C[16384,1024] = A[16384,1024](bf16) @ W^T(bf16 rows) + bo
__launch_bounds__(64)
__global__ void out_gemm(const u16* __restrict__ A, const u16* __restrict__ W,
                         const float* __restrict__ bo, float* __restrict__ C) {
  const int lane = threadIdx.x;
  const int nt4 = blockIdx.x & 15;
  const int mt4 = blockIdx.x >> 4;
  const int r0 = mt4 * 64, n0 = nt4 * 64;
  const int fcol = lane & 15, kg = lane >> 4;
  float4v acc[4][4];
#pragma unroll
  for (int i = 0; i < 4; ++i)
#pragma unroll
    for (int j = 0; j < 4; ++j) acc[i][j] = (float4v){0, 0, 0, 0};

  for (int ks = 0; ks < 32; ++ks) {
    short8 a[4], b[4];
#pragma unroll
    for (int i = 0; i < 4; ++i)
      a[i] = *(const short8*)(A + (size_t)(r0 + i * 16 + fcol) * HH + ks * 32 + kg * 8);
#pragma unroll
    for (int j = 0; j < 4; ++j)
      b[j] = *(const short8*)(W + (size_t)(n0 + j * 16 + fcol) * HH + ks * 32 + kg * 8);
#pragma unroll
    for (int i = 0; i < 4; ++i)
#pragma unroll
      for (int j = 0; j < 4; ++j)
        acc[i][j] = MFMA16(a[i], b[j], acc[i][j]);
  }
#pragma unroll
  for (int i = 0; i < 4; ++i)
#pragma unroll
    for (int j = 0; j < 4; ++j)
#pragma unroll
      for (int q = 0; q < 4; ++q) {
        int R = r0 + i * 16 + kg * 4 + q;
        int col = n0 + j * 16 + fcol;
        C[(size_t)R * OO + col] = acc[i][j][q] + bo[col];
      }
}

extern "C" void kernel_launch(void* const* d_in, const int* in_sizes, int n_in,
                              void* d_out, int out_size, void* d_ws, size_t ws_size,
                              hipStream_t stream) {
  (void)in_sizes; (void)n_in; (void)out_size; (void)ws_size;

  const float* x   = (const float*)d_in[0];
  const float* h0  = (const float*)d_in[1];
  const float* Wzx = (const float*)d_in[2];
  const float* bz  = (const float*)d_in[3];
  const float* Wzh = (const float*)d_in[4];
  const float* Wrx = (const float*)d_in[5];
  const float* br  = (const float*)d_in[6];
  const float* Wrh = (const float*)d_in[7];
  const float* Wgx = (const float*)d_in[8];
  const float* bg  = (const float*)d_in[9];
  const float* Wgh = (const float*)d_in[10];
  const float* Wo  = (const float*)d_in[11];
  const float* bo  = (const float*)d_in[12];
  float* out = (float*)d_out;

  // ws layout (~103 MB)
  u16* Pzh = (u16*)d_ws;
  u16* Pzx = Pzh + 3145728;
  u16* Prh = Pzx + 3145728;
  u16* Prx = Prh + 3145728;
  u16* Pgh = Prx + 3145728;
  u16* Pgx = Pgh + 3145728;
  u16* Wob = Pgx + 3145728;            // 1M elems
  u16* buf0 = Wob + 1048576;           // 16.7M elems
  u16* buf1 = buf0 + 16777216;
  u16* hbw  = buf1 + 16777216;         // [3][B][H]
  u16* rhw  = hbw + 3 * BB * HH;       // [3][B][H]
  int* flagsD = (int*)(rhw + 3 * BB * HH);  // 4 groups x 128
  int* flagsP = flagsD + 512;               // 3 groups x 128

  hipMemsetAsync(flagsD, 0x7F, 128 * sizeof(int), stream);   // dummy producer
  hipMemsetAsync(flagsD + 128, 0, 384 * sizeof(int), stream);
  hipMemsetAsync(flagsP, 0, 384 * sizeof(int), stream);

  pack_w<<<3072, 256, 0, stream>>>(Wzh, Pzh, 3);
  pack_w<<<3072, 256, 0, stream>>>(Wzx, Pzx, 3);
  pack_w<<<3072, 256, 0, stream>>>(Wrh, Prh, 3);
  pack_w<<<3072, 256, 0, stream>>>(Wrx, Prx, 3);
  pack_w<<<3072, 256, 0, stream>>>(Wgh, Pgh, 3);
  pack_w<<<3072, 256, 0, stream>>>(Wgx, Pgx, 3);
  convert_bf16<<<256, 256, 0, stream>>>(Wo, Wob, 1048576);
  convert_bf16<<<2048, 256, 0, stream>>>(x, buf0, 16777216);
  init_h<<<384, 256, 0, stream>>>(h0, hbw);

  gru_pipe<<<192, 256, 0, stream>>>(
      buf0, buf1, Pzh, Pzx, Prh, Prx, Pgh, Pgx,
      bz, br, bg, h0, hbw, rhw, out + 16777216, flagsD, flagsP);

  out_gemm<<<4096, 64, 0, stream>>>(buf1, Wob, bo, out);
}

// Round 12
// 10436.228 us; speedup vs baseline: 3.3280x; 1.4298x over previous
//
#include <hip/hip_runtime.h>
#include <hip/hip_bf16.h>
#include <math.h>

// Multilayer GRU: B=32, S=512, H=1024, L=3, O=1024.
// v12: v11 with all cross-block activations (h, r*h, x/y) in MFMA
// fragment-packed layout: tile(rt,ks) = 1KB contiguous, wave fragment load
// = base + lane*8 -> fully line-coalesced coherent reads (v7/v11's scattered
// 16-rows-per-instruction pattern was transaction-limited at ~1.3TB/s).
// h-state and y-chain unified per layer: slot 0 = h0, slot t+1 = y_t
// (layers 0/1: 128-slot circular + back-pressure; layer 2: full 513 slots,
// consumed by out_gemm in packed form). Producers publish via LDS
// micro-transpose -> two contiguous 512B sc0sc1 stores per tile.

#define BB 32
#define SS 512
#define HH 1024
#define LL 3
#define OO 1024
#define SH (SS*HH)

typedef __attribute__((ext_vector_type(8))) short short8;
typedef __attribute__((ext_vector_type(4))) float float4v;
typedef unsigned long long u64;
typedef unsigned int u32;
typedef unsigned short u16;

__device__ __forceinline__ u16 f2bf(float f) {
  union { float f; u32 u; } v; v.f = f;
  return (u16)((v.u + 0x7FFFu + ((v.u >> 16) & 1u)) >> 16);
}

__global__ void convert_bf16(const float* __restrict__ src,
                             u16* __restrict__ dst, int n) {
  int stride = gridDim.x * blockDim.x;
  for (int i = blockIdx.x * blockDim.x + threadIdx.x; i < n; i += stride)
    dst[i] = f2bf(src[i]);
}

// Pack W[nmat][1024][1024] into MFMA B-fragment stream:
// dst[((row>>4)*32+(k>>5))*512 + lane*8 + (k&7)], lane = ((k>>3)&3)*16+(row&15)
__global__ void pack_w(const float* __restrict__ src, u16* __restrict__ dst,
                       int nmat) {
  int stride = gridDim.x * blockDim.x;
  int total = nmat * 1048576;
  for (int i = blockIdx.x * blockDim.x + threadIdx.x; i < total; i += stride) {
    int m = i >> 20, e = i & 1048575;
    int row = e >> 10, k = e & 1023;
    int lane = ((k >> 3) & 3) * 16 + (row & 15);
    int di = ((row >> 4) * 32 + (k >> 5)) * 512 + lane * 8 + (k & 7);
    dst[m * 1048576 + di] = f2bf(src[i]);
  }
}

// x[B,S,H] fp32 -> packed per-t activation tiles: dst[t*32768 + e],
// e = (rt*32+ks)*512 + lane*8 + j ; b = rt*16+(lane&15), c = ks*32+(lane>>4)*8+j
__global__ void pack_x(const float* __restrict__ x, u16* __restrict__ dst) {
  int stride = gridDim.x * blockDim.x;
  for (int d = blockIdx.x * blockDim.x + threadIdx.x; d < SS * 32768; d += stride) {
    int t = d >> 15, e = d & 32767;
    int rt = e >> 14, ks = (e >> 9) & 31, lane = (e >> 3) & 63, j = e & 7;
    int b = rt * 16 + (lane & 15), c = ks * 32 + ((lane >> 4) << 3) + j;
    dst[d] = f2bf(x[(size_t)b * SH + (size_t)t * HH + c]);
  }
}

// h0[B, L, H] fp32 -> slot 0 of each layer chain (packed)
__global__ void pack_h0(const float* __restrict__ h0, u16* __restrict__ y0,
                        u16* __restrict__ y1, u16* __restrict__ y2) {
  int i = blockIdx.x * 256 + threadIdx.x;   // 98304
  int l = i >> 15, e = i & 32767;
  int rt = e >> 14, ks = (e >> 9) & 31, lane = (e >> 3) & 63, j = e & 7;
  int b = rt * 16 + (lane & 15), c = ks * 32 + ((lane >> 4) << 3) + j;
  u16 v = f2bf(h0[b * (LL * HH) + l * HH + c]);
  u16* dst = (l == 0) ? y0 : ((l == 1) ? y1 : y2);
  dst[e] = v;
}

// ---- access primitives ----------------------------------------------------
__device__ __forceinline__ short8 coh16(const u16* p) {
  const u64* q = (const u64*)p;
  union { u64 q[2]; short8 v; } u;
  u.q[0] = __hip_atomic_load(q,     __ATOMIC_RELAXED, __HIP_MEMORY_SCOPE_AGENT);
  u.q[1] = __hip_atomic_load(q + 1, __ATOMIC_RELAXED, __HIP_MEMORY_SCOPE_AGENT);
  return u.v;
}
__device__ __forceinline__ void coh_store16(u16* p, short8 v) {
  asm volatile("global_store_dwordx4 %0, %1, off sc0 sc1"
               :: "v"(p), "v"(v) : "memory");
}
__device__ __forceinline__ void coh_store_u32(int* p, int v) {
  asm volatile("global_store_dword %0, %1, off sc0 sc1"
               :: "v"(p), "v"(v) : "memory");
}
__device__ __forceinline__ void poll2(const int* base, int lane, int tgt) {
  const int* p0 = base + lane;
  const int* p1 = base + 64 + lane;
  int f0 = __hip_atomic_load(p0, __ATOMIC_RELAXED, __HIP_MEMORY_SCOPE_AGENT);
  int f1 = __hip_atomic_load(p1, __ATOMIC_RELAXED, __HIP_MEMORY_SCOPE_AGENT);
  while (__any((f0 < tgt) | (f1 < tgt))) {
    __builtin_amdgcn_s_sleep(1);
    f0 = __hip_atomic_load(p0, __ATOMIC_RELAXED, __HIP_MEMORY_SCOPE_AGENT);
    f1 = __hip_atomic_load(p1, __ATOMIC_RELAXED, __HIP_MEMORY_SCOPE_AGENT);
  }
}

#define MFMA16(a, b, c) __builtin_amdgcn_mfma_f32_16x16x32_bf16(a, b, c, 0, 0, 0)

__launch_bounds__(256, 1)
__global__ void gru_pipe(
    const u16* __restrict__ xpk0,
    u16* __restrict__ ypk0, u16* __restrict__ ypk1, u16* __restrict__ ypk2,
    const u16* __restrict__ Pzh, const u16* __restrict__ Pzx,
    const u16* __restrict__ Prh, const u16* __restrict__ Prx,
    const u16* __restrict__ Pgh, const u16* __restrict__ Pgx,
    const float* __restrict__ bz, const float* __restrict__ br,
    const float* __restrict__ bg, const float* __restrict__ h0,
    u16* __restrict__ rhA, float* __restrict__ hid,
    int* __restrict__ flagsD, int* __restrict__ flagsP) {
  __shared__ __align__(16) u16 smW[3][16384];     // Wzh, Wrh, Wgh (96 KB)
  __shared__ float redz[4][2][64], redr[4][2][64], redg[4][2][64];
  __shared__ __align__(16) u16 pubP[2][256];      // per-mt packed publish buf

  const int grp = blockIdx.x >> 6;        // layer 0..2
  const int blk = blockIdx.x & 63;        // 16-col tile
  const int tid = threadIdx.x;
  const int lane = tid & 63;
  const int wave = tid >> 6;
  const int mt = wave & 1;                // M-tile: rows 0-15 / 16-31
  const int kh = wave >> 1;               // phase1 side: 0=h, 1=x
  const int fcol = lane & 15, kg = lane >> 4;
  const int crow0 = mt * 16 + kg * 4;
  const int colZ = blk * 16 + fcol;

  u16* ypkl       = (grp == 0) ? ypk0 : ((grp == 1) ? ypk1 : ypk2);
  const u16* ypkp = (grp == 1) ? ypk0 : ypk1;   // producer chain (grp>=1)
  const bool circ = (grp < 2);
  const size_t lw = (size_t)grp * 1048576;
  const u16* wZx = Pzx + lw + blk * 16384 + lane * 8;
  const u16* wRx = Prx + lw + blk * 16384 + lane * 8;
  const u16* wGx = Pgx + lw + blk * 16384 + lane * 8;
  u16* rhl = rhA + grp * (BB * HH);
  int* selfD = flagsD + (grp + 1) * 128;
  int* prodD = flagsD + grp * 128;
  int* consD = flagsD + (grp + 2) * 128;  // valid only grp<2
  int* selfP = flagsP + grp * 128;

  // ---- stage h-side weight slices into LDS (once) -------------------------
  {
    const u64* g0 = (const u64*)(Pzh + lw + blk * 16384);
    const u64* g1 = (const u64*)(Prh + lw + blk * 16384);
    const u64* g2 = (const u64*)(Pgh + lw + blk * 16384);
    u64* d0 = (u64*)smW[0];
    u64* d1 = (u64*)smW[1];
    u64* d2 = (u64*)smW[2];
#pragma unroll
    for (int j = 0; j < 16; ++j) {
      d0[j * 256 + tid] = g0[j * 256 + tid];
      d1[j * 256 + tid] = g1[j * 256 + tid];
      d2[j * 256 + tid] = g2[j * 256 + tid];
    }
  }
  __syncthreads();
  const u16* lZ = smW[0] + lane * 8;
  const u16* lR = smW[1] + lane * 8;
  const u16* lG = smW[2] + lane * 8;

  float hreg[4] = {0, 0, 0, 0}, zreg[4] = {0, 0, 0, 0};
  float bzv = 0, brv = 0, bgv = 0;
  if (kh == 0) {
#pragma unroll
    for (int q = 0; q < 4; ++q)
      hreg[q] = h0[(crow0 + q) * (LL * HH) + grp * HH + colZ];
    bzv = bz[grp * HH + colZ];
    brv = br[grp * HH + colZ];
    bgv = bg[grp * HH + colZ];
  }

  // producer-half publish target within a packed tile
  const int pubOff = (mt * 32 + (blk >> 1)) * 512 + (blk & 1) * 256;

  for (int t = 0; t < SS; ++t) {
    const int hslot = circ ? (t & 127) : t;
    const int wslot = circ ? ((t + 1) & 127) : (t + 1);

    // ---- phase-1 gate (per-wave) ----------------------------------------
    if (kh == 0) {
      poll2(selfD, lane, t);                       // own-layer WAR
      if (circ && t >= 128) poll2(consD, lane, t - 127);  // chain back-pressure
    } else if (grp != 0) {
      poll2(prodD, lane, t + 1);                   // producer published y[t]
    }

    float4v az0 = {0,0,0,0}, az1 = {0,0,0,0};
    float4v ar0 = {0,0,0,0}, ar1 = {0,0,0,0};
    float4v ag0 = {0,0,0,0}, ag1 = {0,0,0,0};
    short8 cf[16];

    if (kh == 0) {
      // ---- h-side z,r GEMM: A packed-coherent, B from LDS ----
      const u16* hbase = ypkl + (size_t)hslot * 32768 + mt * 16384 + lane * 8;
#pragma unroll
      for (int c0 = 0; c0 < 32; c0 += 16) {
#pragma unroll
        for (int k = 0; k < 16; ++k)
          cf[k] = coh16(hbase + (c0 + k) * 512);
#pragma unroll
        for (int k = 0; k < 16; ++k) {
          short8 vz = *(const short8*)(lZ + (c0 + k) * 512);
          short8 vr = *(const short8*)(lR + (c0 + k) * 512);
          if (k & 1) { az1 = MFMA16(cf[k], vz, az1); ar1 = MFMA16(cf[k], vr, ar1); }
          else       { az0 = MFMA16(cf[k], vz, az0); ar0 = MFMA16(cf[k], vr, ar0); }
        }
      }
    } else {
      // ---- x-side z,r (+gx) GEMM: A packed, B streamed ----
      const u16* xbase = (grp == 0)
          ? (xpk0 + (size_t)t * 32768 + mt * 16384 + lane * 8)
          : (ypkp + (size_t)((t + 1) & 127) * 32768 + mt * 16384 + lane * 8);
#pragma unroll
      for (int c0 = 0; c0 < 32; c0 += 16) {
        if (grp != 0) {
#pragma unroll
          for (int k = 0; k < 16; ++k) cf[k] = coh16(xbase + (c0 + k) * 512);
        } else {
#pragma unroll
          for (int k = 0; k < 16; ++k) cf[k] = *(const short8*)(xbase + (c0 + k) * 512);
        }
#pragma unroll
        for (int k = 0; k < 16; ++k) {
          int ks = c0 + k;
          short8 vz = *(const short8*)(wZx + ks * 512);
          short8 vr = *(const short8*)(wRx + ks * 512);
          short8 vg = *(const short8*)(wGx + ks * 512);
          if (k & 1) { az1 = MFMA16(cf[k], vz, az1); ar1 = MFMA16(cf[k], vr, ar1);
                       ag1 = MFMA16(cf[k], vg, ag1); }
          else       { az0 = MFMA16(cf[k], vz, az0); ar0 = MFMA16(cf[k], vr, ar0);
                       ag0 = MFMA16(cf[k], vg, ag0); }
        }
      }
#pragma unroll
      for (int q = 0; q < 4; ++q) {
        redz[q][mt][lane] = az0[q] + az1[q];
        redr[q][mt][lane] = ar0[q] + ar1[q];
      }
    }
    __syncthreads();

    if (kh == 0) {
      // finalize z,r; packed-publish r*h (one dwordx4/lane over 32 lanes)
#pragma unroll
      for (int q = 0; q < 4; ++q) {
        float pz = az0[q] + az1[q] + redz[q][mt][lane] + bzv;
        float pr = ar0[q] + ar1[q] + redr[q][mt][lane] + brv;
        zreg[q] = 1.f / (1.f + expf(-pz));
        float rv = 1.f / (1.f + expf(-pr));
        pubP[mt][(((fcol >> 3) << 4) + kg * 4 + q) * 8 + (fcol & 7)] =
            f2bf(rv * hreg[q]);
      }
      asm volatile("s_waitcnt lgkmcnt(0)" ::: "memory");
      __builtin_amdgcn_sched_barrier(0);
      if (lane < 32) {
        short8 v = *(const short8*)(pubP[mt] + lane * 8);
        coh_store16(rhl + pubOff + lane * 8, v);
      }
      asm volatile("s_waitcnt vmcnt(0)" ::: "memory");
      if (lane == 0) coh_store_u32(selfP + blk * 2 + mt, t + 1);
    }

    // ---- phase-2 gate: all r*h published
    poll2(selfP, lane, t + 1);

    // rh frags (packed): 16 chunks per wave (K split by kh); B from LDS
    {
      const u16* rbase = rhl + mt * 16384 + kh * 8192 + lane * 8;
#pragma unroll
      for (int k = 0; k < 16; ++k) cf[k] = coh16(rbase + k * 512);
#pragma unroll
      for (int k = 0; k < 16; ++k) {
        short8 vg = *(const short8*)(lG + (kh * 16 + k) * 512);
        if (k & 1) ag1 = MFMA16(cf[k], vg, ag1);
        else       ag0 = MFMA16(cf[k], vg, ag0);
      }
    }
    if (kh == 1) {
#pragma unroll
      for (int q = 0; q < 4; ++q) redg[q][mt][lane] = ag0[q] + ag1[q];
    }
    __syncthreads();

    if (kh == 0) {
#pragma unroll
      for (int q = 0; q < 4; ++q) {
        float pg = ag0[q] + ag1[q] + redg[q][mt][lane] + bgv;
        float gv = tanhf(pg);
        float hn = zreg[q] * hreg[q] + (1.f - zreg[q]) * gv;
        hreg[q] = hn;
        pubP[mt][(((fcol >> 3) << 4) + kg * 4 + q) * 8 + (fcol & 7)] = f2bf(hn);
        if (t == SS - 1) hid[(crow0 + q) * (LL * HH) + grp * HH + colZ] = hn;
      }
      asm volatile("s_waitcnt lgkmcnt(0)" ::: "memory");
      __builtin_amdgcn_sched_barrier(0);
      if (lane < 32) {
        short8 v = *(const short8*)(pubP[mt] + lane * 8);
        coh_store16(ypkl + (size_t)wslot * 32768 + pubOff + lane * 8, v);
      }
      asm volatile("s_waitcnt vmcnt(0)" ::: "memory");
      if (lane == 0) coh_store_u32(selfD + blk * 2 + mt, t + 1);
    }
  }
}

// layer_output[b,s,:] = y2[b][s][:] @ Wo^T + bo, A read in packed form
__launch_bounds__(64)
__global__ void out_gemm(const u16* __restrict__ ypk2, const u16* __restrict__ W,
                         const float* __restrict__ bo, float* __restrict__ C) {
  const int lane = threadIdx.x;
  const int nt4 = blockIdx.x & 15;
  const int sb = blockIdx.x >> 4;   // 0..1023
  const int s = sb >> 1, bt = sb & 1;
  const int n0 = nt4 * 64;
  const int fcol = lane & 15, kg = lane >> 4;
  const u16* Abase = ypk2 + (size_t)(s + 1) * 32768 + bt * 16384 + lane * 8;
  float4v acc[4];
#pragma unroll
  for (int j = 0; j < 4; ++j) acc[j] = (float4v){0, 0, 0, 0};

  for (int ks = 0; ks < 32; ++ks) {
    short8 a = *(const short8*)(Abase + ks * 512);
#pragma unroll
    for (int j = 0; j < 4; ++j) {
      short8 b = *(const short8*)(W + (size_t)(n0 + j * 16 + fcol) * HH + ks * 32 + kg * 8);
      acc[j] = MFMA16(a, b, acc[j]);
    }
  }
#pragma unroll
  for (int j = 0; j < 4; ++j)
#pragma unroll
    for (int q = 0; q < 4; ++q) {
      int b = bt * 16 + kg * 4 + q;
      int col = n0 + j * 16 + fcol;
      C[((size_t)b * SS + s) * OO + col] = acc[j][q] + bo[col];
    }
}

extern "C" void kernel_launch(void* const* d_in, const int* in_sizes, int n_in,
                              void* d_out, int out_size, void* d_ws, size_t ws_size,
                              hipStream_t stream) {
  (void)in_sizes; (void)n_in; (void)out_size; (void)ws_size;

  const float* x   = (const float*)d_in[0];
  const float* h0  = (const float*)d_in[1];
  const float* Wzx = (const float*)d_in[2];
  const float* bz  = (const float*)d_in[3];
  const float* Wzh = (const float*)d_in[4];
  const float* Wrx = (const float*)d_in[5];
  const float* br  = (const float*)d_in[6];
  const float* Wrh = (const float*)d_in[7];
  const float* Wgx = (const float*)d_in[8];
  const float* bg  = (const float*)d_in[9];
  const float* Wgh = (const float*)d_in[10];
  const float* Wo  = (const float*)d_in[11];
  const float* bo  = (const float*)d_in[12];
  float* out = (float*)d_out;

  // ws layout (~124 MB)
  u16* Pzh = (u16*)d_ws;
  u16* Pzx = Pzh + 3145728;
  u16* Prh = Pzx + 3145728;
  u16* Prx = Prh + 3145728;
  u16* Pgh = Prx + 3145728;
  u16* Pgx = Pgh + 3145728;
  u16* Wob = Pgx + 3145728;                 // 1M elems
  u16* xpk0 = Wob + 1048576;                // [512][32768]
  u16* ypk0 = xpk0 + 16777216;              // [128][32768] circular
  u16* ypk1 = ypk0 + 128 * 32768;           // [128][32768] circular
  u16* ypk2 = ypk1 + 128 * 32768;           // [513][32768]
  u16* rhA  = ypk2 + 513 * 32768;           // [3][32768]
  int* flagsD = (int*)(rhA + 3 * 32768);    // 5 groups x 128 (cons gate uses +2)
  int* flagsP = flagsD + 640;               // 3 groups x 128

  hipMemsetAsync(flagsD, 0x7F, 128 * sizeof(int), stream);   // dummy producer
  hipMemsetAsync(flagsD + 128, 0, 512 * sizeof(int), stream);
  hipMemsetAsync(flagsP, 0, 384 * sizeof(int), stream);

  pack_w<<<3072, 256, 0, stream>>>(Wzh, Pzh, 3);
  pack_w<<<3072, 256, 0, stream>>>(Wzx, Pzx, 3);
  pack_w<<<3072, 256, 0, stream>>>(Wrh, Prh, 3);
  pack_w<<<3072, 256, 0, stream>>>(Wrx, Prx, 3);
  pack_w<<<3072, 256, 0, stream>>>(Wgh, Pgh, 3);
  pack_w<<<3072, 256, 0, stream>>>(Wgx, Pgx, 3);
  convert_bf16<<<256, 256, 0, stream>>>(Wo, Wob, 1048576);
  pack_x<<<4096, 256, 0, stream>>>(x, xpk0);
  pack_h0<<<384, 256, 0, stream>>>(h0, ypk0, ypk1, ypk2);

  gru_pipe<<<192, 256, 0, stream>>>(
      xpk0, ypk0, ypk1, ypk2,
      Pzh, Pzx, Prh, Prx, Pgh, Pgx,
      bz, br, bg, h0, rhA, out + 16777216, flagsD, flagsP);

  out_gemm<<<16384, 64, 0, stream>>>(ypk2, Wob, bo, out);
}